// Round 10
// baseline (924.357 us; speedup 1.0000x reference)
//
#include <hip/hip_runtime.h>

#define NF 32
#define EPSF 1e-9f

// concatenated keyspaces
// sort:  [0,262144) morton3@64 ; [262144 + g*65536) pair g morton2@256   (KSORT=458752)
// visit: R16 [0,4096) R32 [4096,36864) R64 [36864,299008)
//        64^2 [299008 + g*4096) 128^2 [311296 + g*16384) 256^2 [360448 + g*65536)  (KVIS=557056)
#define KSORT 458752
#define KVIS 557056
#define KO16 0
#define KO32 4096
#define KO64 36864
#define KO64Q 299008
#define KO128Q 311296
#define KO256Q 360448

__device__ __forceinline__ int cell_coord(float xv, int R, float& fr) {
  float x = xv * (float)(R - 1);
  int i0 = (int)floorf(x);
  i0 = min(max(i0, 0), R - 2);
  fr = x - (float)i0;
  return i0;
}
__device__ __forceinline__ float bf2f(unsigned short u) {
  return __uint_as_float((unsigned)u << 16);
}
__device__ __forceinline__ unsigned short f2bf(float x) {
  unsigned b = __float_as_uint(x);
  return (unsigned short)((b + 0x7FFF + ((b >> 16) & 1)) >> 16);
}
__device__ __forceinline__ unsigned p1b2(unsigned x) {
  x &= 0x3FF;
  x = (x | (x << 16)) & 0x030000FF;
  x = (x | (x << 8)) & 0x0300F00F;
  x = (x | (x << 4)) & 0x030C30C3;
  x = (x | (x << 2)) & 0x09249249;
  return x;
}
__device__ __forceinline__ unsigned p1b1(unsigned x) {
  x &= 0xFFFF;
  x = (x | (x << 8)) & 0x00FF00FF;
  x = (x | (x << 4)) & 0x0F0F0F0F;
  x = (x | (x << 2)) & 0x33333333;
  x = (x | (x << 1)) & 0x55555555;
  return x;
}

// XCD-aware bijective swizzle: contiguous chunk per XCD (requires n % 8 == 0)
__device__ __forceinline__ int xcd_swz(int bid, int n) {
  return (bid & 7) * (n >> 3) + (bid >> 3);
}

// ---- wave-aggregated atomics over sorted-ish keys ----
__device__ __forceinline__ void agg_hist(int key, int* cnt) {
  int lane = threadIdx.x & 63;
  unsigned long long amask = __ballot(1);
  int nact = __popcll(amask);
  int prev = __shfl_up(key, 1);
  bool leader = (lane == 0) || (prev != key);
  unsigned long long lmask = __ballot(leader);
  if (leader) {
    unsigned long long above = (lane < 63) ? (lmask >> (lane + 1)) : 0ULL;
    int next = above ? (lane + 1 + (__ffsll((unsigned long long)above) - 1)) : nact;
    atomicAdd(&cnt[key], next - lane);
  }
}
__device__ __forceinline__ int agg_place(int key, int* cur) {
  int lane = threadIdx.x & 63;
  unsigned long long amask = __ballot(1);
  int nact = __popcll(amask);
  int prev = __shfl_up(key, 1);
  bool leader = (lane == 0) || (prev != key);
  unsigned long long lmask = __ballot(leader);
  unsigned long long below = lmask & ((2ULL << lane) - 1ULL);
  int lp = 63 - __clzll((long long)below);
  int base = 0;
  if (leader) {
    unsigned long long above = (lane < 63) ? (lmask >> (lane + 1)) : 0ULL;
    int next = above ? (lane + 1 + (__ffsll((unsigned long long)above) - 1)) : nact;
    base = atomicAdd(&cur[key], next - lane);
  }
  base = __shfl(base, lp);
  return base + (lane - lp);
}

// ---------------- fused sort keys: morton3@64 + 3 pair keys@256 ----------------
__global__ __launch_bounds__(256) void sort_hist_all(
    const float* __restrict__ xyz, int* __restrict__ cnt, int N) {
  int p = blockIdx.x * blockDim.x + threadIdx.x;
  if (p >= N) return;
  float fr;
  int c64[3], c256[3];
#pragma unroll
  for (int d = 0; d < 3; ++d) {
    c64[d] = cell_coord(xyz[p * 3 + d], 64, fr);
    c256[d] = cell_coord(xyz[p * 3 + d], 256, fr);
  }
  int k3 = (int)((p1b2((unsigned)c64[0]) << 2) | (p1b2((unsigned)c64[1]) << 1) |
                 p1b2((unsigned)c64[2]));
  atomicAdd(&cnt[k3], 1);
#pragma unroll
  for (int g = 0; g < 3; ++g) {
    int a = (g < 2) ? 0 : 1, b = (g == 0) ? 1 : 2;
    int key = 262144 + g * 65536 +
              (int)((p1b1((unsigned)c256[a]) << 1) | p1b1((unsigned)c256[b]));
    atomicAdd(&cnt[key], 1);
  }
}
__global__ __launch_bounds__(256) void sort_place_all(
    const float* __restrict__ xyz, int* __restrict__ cur, int* __restrict__ perm, int N) {
  int p = blockIdx.x * blockDim.x + threadIdx.x;
  if (p >= N) return;
  float fr;
  int c64[3], c256[3];
#pragma unroll
  for (int d = 0; d < 3; ++d) {
    c64[d] = cell_coord(xyz[p * 3 + d], 64, fr);
    c256[d] = cell_coord(xyz[p * 3 + d], 256, fr);
  }
  int k3 = (int)((p1b2((unsigned)c64[0]) << 2) | (p1b2((unsigned)c64[1]) << 1) |
                 p1b2((unsigned)c64[2]));
  perm[atomicAdd(&cur[k3], 1)] = p;
#pragma unroll
  for (int g = 0; g < 3; ++g) {
    int a = (g < 2) ? 0 : 1, b = (g == 0) ? 1 : 2;
    int key = 262144 + g * 65536 +
              (int)((p1b1((unsigned)c256[a]) << 1) | p1b1((unsigned)c256[b]));
    perm[atomicAdd(&cur[key], 1)] = p;
  }
}
__global__ __launch_bounds__(256) void permute_all(
    const float* __restrict__ xyz, const float* __restrict__ feat,
    const int* __restrict__ perm, float* __restrict__ xyz_s,
    unsigned short* __restrict__ feat_s, float* __restrict__ xy_g,
    unsigned short* __restrict__ feat_g, int N) {
  int t = blockIdx.x * blockDim.x + threadIdx.x;
  int s = t >> 5, f = t & 31;
  if (s >= 4 * N) return;
  int q = perm[s];
  float v = feat[(size_t)q * NF + f];
  if (s < N) {
    feat_s[(size_t)s * NF + f] = f2bf(v);
    if (f < 3) xyz_s[s * 3 + f] = xyz[q * 3 + f];
  } else {
    int sl = s - N;
    int g = sl / N;
    feat_g[(size_t)sl * NF + f] = f2bf(v);
    if (f < 2) {
      int a = (g < 2) ? 0 : 1, b = (g == 0) ? 1 : 2;
      xy_g[(size_t)sl * 2 + f] = xyz[q * 3 + (f == 0 ? a : b)];
    }
  }
}

// ---------------- scan (hierarchical, exclusive) ----------------
__global__ __launch_bounds__(256) void scan_blocksum(
    const int* __restrict__ cnt, int* __restrict__ bsum, int K) {
  __shared__ int red[256];
  int base = blockIdx.x * 2048 + threadIdx.x * 8;
  int s = 0;
#pragma unroll
  for (int j = 0; j < 8; ++j) {
    int k = base + j;
    if (k < K) s += cnt[k];
  }
  red[threadIdx.x] = s;
  __syncthreads();
  for (int off = 128; off > 0; off >>= 1) {
    if (threadIdx.x < off) red[threadIdx.x] += red[threadIdx.x + off];
    __syncthreads();
  }
  if (threadIdx.x == 0) bsum[blockIdx.x] = red[0];
}
__global__ __launch_bounds__(256) void scan_write(
    const int* __restrict__ cnt, const int* __restrict__ bsum,
    int* __restrict__ cur, int K) {
  __shared__ int lds[256];
  __shared__ int boff;
  int b = blockIdx.x, t = threadIdx.x;
  if (t == 0) {
    int s = 0;
    for (int j = 0; j < b; ++j) s += bsum[j];
    boff = s;
  }
  int base = b * 2048 + t * 8;
  int v[8];
  int s = 0;
#pragma unroll
  for (int j = 0; j < 8; ++j) {
    int k = base + j;
    v[j] = (k < K) ? cnt[k] : 0;
    s += v[j];
  }
  lds[t] = s;
  __syncthreads();
  for (int off = 1; off < 256; off <<= 1) {
    int add = (t >= off) ? lds[t - off] : 0;
    __syncthreads();
    lds[t] += add;
    __syncthreads();
  }
  int run = boff + lds[t] - s;
#pragma unroll
  for (int j = 0; j < 8; ++j) {
    int k = base + j;
    if (k < K) {
      cur[k] = run;
      run += v[j];
    }
  }
}

// ---------------- visit emission: one (resolution, corner) slice per blockIdx.y ----------------
template <int PHASE>
__global__ __launch_bounds__(256) void visit3_all(
    const float* __restrict__ xyz, int* __restrict__ cnt, int* __restrict__ cur,
    int2* __restrict__ visits, int N) {
  int y = blockIdx.y;          // 0..23 : r*8 + cb
  int r = y >> 3, cb = y & 7;
  int p = blockIdx.x * blockDim.x + threadIdx.x;
  if (p >= N) return;
  const int RS[3] = {16, 32, 64};
  const int KO[3] = {KO16, KO32, KO64};
  int R = RS[r];
  float w = 1.f;
  unsigned key = 0;
#pragma unroll
  for (int d = 0; d < 3; ++d) {
    float fr;
    int i0 = cell_coord(xyz[p * 3 + d], R, fr);
    int o = (cb >> d) & 1;
    w *= o ? fr : (1.f - fr);
    key |= p1b2((unsigned)(i0 + o)) << (2 - d);
  }
  int k = KO[r] + (int)key;
  if (PHASE == 0) {
    agg_hist(k, cnt);
  } else {
    int pos = agg_place(k, cur);
    visits[pos] = make_int2(p, __float_as_int(w));
  }
}

template <int PHASE>
__global__ __launch_bounds__(256) void visit2_all(
    const float* __restrict__ xy_g, int* __restrict__ cnt, int* __restrict__ cur,
    int2* __restrict__ visits, int N) {
  int y = blockIdx.y;          // 0..35 : g*12 + r*4 + cb
  int g = y / 12;
  int rc = y % 12;
  int r = rc >> 2, cb = rc & 3;
  int p = blockIdx.x * blockDim.x + threadIdx.x;
  if (p >= N) return;
  int sl = g * N + p;
  const int RS[3] = {64, 128, 256};
  const int KB[3] = {KO64Q, KO128Q, KO256Q};
  const int RSQ[3] = {4096, 16384, 65536};
  int R = RS[r];
  float frx, fry;
  int ix = cell_coord(xy_g[(size_t)sl * 2 + 0], R, frx);
  int iy = cell_coord(xy_g[(size_t)sl * 2 + 1], R, fry);
  int o0 = (cb >> 1) & 1, o1 = cb & 1;
  float w = (o0 ? frx : 1.f - frx) * (o1 ? fry : 1.f - fry);
  int k = KB[r] + g * RSQ[r] +
          (int)((p1b1((unsigned)(ix + o0)) << 1) | p1b1((unsigned)(iy + o1)));
  if (PHASE == 0) {
    agg_hist(k, cnt);
  } else {
    int pos = agg_place(k, cur);
    visits[pos] = make_int2(sl, __float_as_int(w));
  }
}

// ---------------- create: block-per-cell, segment-local XCD swizzle ----------------
__global__ __launch_bounds__(256) void create_block(
    const unsigned short* __restrict__ feat, const int* __restrict__ cnt,
    const int* __restrict__ cur_end, const int2* __restrict__ visits,
    unsigned short* __restrict__ grid, int CBASE) {
  __shared__ int2 vlds[1024];
  __shared__ float lacc[256];
  __shared__ float lw[8];
  int cell = CBASE + xcd_swz(blockIdx.x, gridDim.x);
  int e = cur_end[cell];
  int n = cnt[cell];
  int beg = e - n;
  for (int i = threadIdx.x; i < n && i < 1024; i += 256) vlds[i] = visits[beg + i];
  __syncthreads();
  bool inl = (n <= 1024);
  int slot = threadIdx.x >> 5;
  int f = threadIdx.x & 31;
  float acc = 0.f, wsum = 0.f;
  int i = slot;
  for (; i + 24 < n; i += 32) {
    int2 v0 = inl ? vlds[i] : visits[beg + i];
    int2 v1 = inl ? vlds[i + 8] : visits[beg + i + 8];
    int2 v2 = inl ? vlds[i + 16] : visits[beg + i + 16];
    int2 v3 = inl ? vlds[i + 24] : visits[beg + i + 24];
    float f0 = bf2f(feat[(size_t)v0.x * NF + f]);
    float f1 = bf2f(feat[(size_t)v1.x * NF + f]);
    float f2 = bf2f(feat[(size_t)v2.x * NF + f]);
    float f3 = bf2f(feat[(size_t)v3.x * NF + f]);
    float w0 = __int_as_float(v0.y), w1 = __int_as_float(v1.y);
    float w2 = __int_as_float(v2.y), w3 = __int_as_float(v3.y);
    acc = fmaf(w0, f0, acc);
    acc = fmaf(w1, f1, acc);
    acc = fmaf(w2, f2, acc);
    acc = fmaf(w3, f3, acc);
    wsum += (w0 + w1) + (w2 + w3);
  }
  for (; i < n; i += 8) {
    int2 v = inl ? vlds[i] : visits[beg + i];
    float w = __int_as_float(v.y);
    acc = fmaf(w, bf2f(feat[(size_t)v.x * NF + f]), acc);
    wsum += w;
  }
  lacc[threadIdx.x] = acc;
  if (f == 0) lw[slot] = wsum;
  __syncthreads();
  if (slot == 0) {
    float a = 0.f, w = 0.f;
#pragma unroll
    for (int s = 0; s < 8; ++s) {
      a += lacc[s * 32 + f];
      w += lw[s];
    }
    grid[(size_t)cell * NF + f] = f2bf(a / fmaxf(w, EPSF));
  }
}

// ---------------- create: wave-per-cell (4/block), segment-local XCD swizzle ----------------
__global__ __launch_bounds__(256) void create_wave4(
    const unsigned short* __restrict__ feat, const int* __restrict__ cnt,
    const int* __restrict__ cur_end, const int2* __restrict__ visits,
    unsigned short* __restrict__ grid, int CBASE, int K) {
  __shared__ int2 vlds[1024];
  int wave = threadIdx.x >> 6, lane = threadIdx.x & 63;
  int f = lane & 31, half = lane >> 5;
  int c0 = CBASE + xcd_swz(blockIdx.x, gridDim.x) * 4;
  int lastc = min(c0 + 3, CBASE + K - 1);
  int vbase = cur_end[c0] - cnt[c0];
  int vlen = cur_end[lastc] - vbase;
  for (int i = threadIdx.x; i < vlen && i < 1024; i += 256) vlds[i] = visits[vbase + i];
  __syncthreads();
  int cell = c0 + wave;
  if (cell > lastc) return;
  int e = cur_end[cell];
  int n = cnt[cell];
  int beg = e - n;
  bool inl = (e - vbase) <= 1024;
  int b0 = beg - vbase;
  float acc = 0.f, wsum = 0.f;
  int i = half;
  for (; i + 2 < n; i += 4) {
    int2 v0 = inl ? vlds[b0 + i] : visits[beg + i];
    int2 v1 = inl ? vlds[b0 + i + 2] : visits[beg + i + 2];
    float w0 = __int_as_float(v0.y), w1 = __int_as_float(v1.y);
    float f0 = bf2f(feat[(size_t)v0.x * NF + f]);
    float f1 = bf2f(feat[(size_t)v1.x * NF + f]);
    acc = fmaf(w0, f0, acc);
    wsum += w0;
    acc = fmaf(w1, f1, acc);
    wsum += w1;
  }
  for (; i < n; i += 2) {
    int2 v = inl ? vlds[b0 + i] : visits[beg + i];
    float w = __int_as_float(v.y);
    acc = fmaf(w, bf2f(feat[(size_t)v.x * NF + f]), acc);
    wsum += w;
  }
  acc += __shfl_xor(acc, 32);
  wsum += __shfl_xor(wsum, 32);
  if (half == 0) grid[(size_t)cell * NF + f] = f2bf(acc / fmaxf(wsum, EPSF));
}

// ---------------- fused encode: all 12 slots ----------------
__global__ __launch_bounds__(256) void encode_all(
    const float* __restrict__ xyz, const unsigned short* __restrict__ grid,
    float* __restrict__ out, int M) {
  int t = blockIdx.x * blockDim.x + threadIdx.x;
  int m = t >> 5, f = t & 31;
  if (m >= M) return;
  float X[3];
#pragma unroll
  for (int d = 0; d < 3; ++d) X[d] = xyz[m * 3 + d];
  // 3D slots 0..2
  {
    const int RS[3] = {16, 32, 64};
    const int KO[3] = {KO16, KO32, KO64};
#pragma unroll
    for (int r = 0; r < 3; ++r) {
      unsigned a0[3], a1[3];
      float fr[3];
#pragma unroll
      for (int d = 0; d < 3; ++d) {
        int i0 = cell_coord(X[d], RS[r], fr[d]);
        a0[d] = p1b2((unsigned)i0);
        a1[d] = p1b2((unsigned)(i0 + 1));
      }
      float acc = 0.f;
#pragma unroll
      for (int cb = 0; cb < 8; ++cb) {
        float w = 1.f;
        unsigned key = 0;
#pragma unroll
        for (int d = 0; d < 3; ++d) {
          int o = (cb >> d) & 1;
          w *= o ? fr[d] : (1.f - fr[d]);
          key |= (o ? a1[d] : a0[d]) << (2 - d);
        }
        acc = fmaf(w, bf2f(grid[(size_t)(KO[r] + (int)key) * NF + f]), acc);
      }
      out[(size_t)m * 384 + r * 32 + f] = acc;
    }
  }
  // 2D slots 3..11
  {
    const int RS[3] = {64, 128, 256};
    const int KB[3] = {KO64Q, KO128Q, KO256Q};
    const int RSQ[3] = {4096, 16384, 65536};
#pragma unroll
    for (int r = 0; r < 3; ++r) {
      unsigned b0[3], b1[3];
      float fr[3];
#pragma unroll
      for (int d = 0; d < 3; ++d) {
        int i0 = cell_coord(X[d], RS[r], fr[d]);
        b0[d] = p1b1((unsigned)i0);
        b1[d] = p1b1((unsigned)(i0 + 1));
      }
#pragma unroll
      for (int g = 0; g < 3; ++g) {
        int a = (g < 2) ? 0 : 1, b = (g == 0) ? 1 : 2;
        int base = KB[r] + g * RSQ[r];
        float acc = 0.f;
#pragma unroll
        for (int cb = 0; cb < 4; ++cb) {
          int o0 = (cb >> 1) & 1, o1 = cb & 1;
          float w = (o0 ? fr[a] : 1.f - fr[a]) * (o1 ? fr[b] : 1.f - fr[b]);
          int k = base + (int)(((o0 ? b1[a] : b0[a]) << 1) | (o1 ? b1[b] : b0[b]));
          acc = fmaf(w, bf2f(grid[(size_t)k * NF + f]), acc);
        }
        out[(size_t)m * 384 + (3 + g * 3 + r) * 32 + f] = acc;
      }
    }
  }
}

extern "C" void kernel_launch(void* const* d_in, const int* in_sizes, int n_in,
                              void* d_out, int out_size, void* d_ws, size_t ws_size,
                              hipStream_t stream) {
  const float* xyz_c = (const float*)d_in[0];
  const float* xyz_i = (const float*)d_in[1];
  const float* feat = (const float*)d_in[2];
  float* out = (float*)d_out;
  int N = in_sizes[0] / 3;
  int M = in_sizes[1] / 3;

  char* wsb = (char*)d_ws;
  size_t off = 0;
  auto al = [&](size_t bytes) {
    size_t o = off;
    off = (off + bytes + 255) & ~(size_t)255;
    return wsb + o;
  };
  const int KALL = KSORT + KVIS;
  int* cnt_all = (int*)al((size_t)KALL * 4);
  int* cur_all = (int*)al((size_t)KALL * 4);
  int* bsum = (int*)al(4096);
  int* perm = (int*)al((size_t)4 * N * 4);
  float* xyz_s = (float*)al((size_t)N * 3 * 4);
  unsigned short* feat_s = (unsigned short*)al((size_t)N * NF * 2);
  float* xy_g = (float*)al((size_t)3 * N * 2 * 4);
  unsigned short* feat_g = (unsigned short*)al((size_t)3 * N * NF * 2);
  int2* visits = (int2*)al((size_t)60 * N * 8);
  unsigned short* grid = (unsigned short*)al((size_t)KVIS * NF * 2);

  int* cnt_v = cnt_all + KSORT;
  int* cur_v = cur_all + KSORT;

  int pb = (N + 255) / 256;
  int nbs = (KSORT + 2047) / 2048;
  int nbv = (KVIS + 2047) / 2048;

  hipMemsetAsync(cnt_all, 0, (size_t)KALL * 4, stream);

  // fused sort of all 4 point-orderings
  sort_hist_all<<<pb, 256, 0, stream>>>(xyz_c, cnt_all, N);
  scan_blocksum<<<nbs, 256, 0, stream>>>(cnt_all, bsum, KSORT);
  scan_write<<<nbs, 256, 0, stream>>>(cnt_all, bsum, cur_all, KSORT);
  sort_place_all<<<pb, 256, 0, stream>>>(xyz_c, cur_all, perm, N);
  permute_all<<<(4 * N * 32 + 255) / 256, 256, 0, stream>>>(xyz_c, feat, perm, xyz_s,
                                                            feat_s, xy_g, feat_g, N);

  // visit emission: one (resolution, corner) slice per blockIdx.y
  visit3_all<0><<<dim3(pb, 24), 256, 0, stream>>>(xyz_s, cnt_v, cur_v, visits, N);
  visit2_all<0><<<dim3(pb, 36), 256, 0, stream>>>(xy_g, cnt_v, cur_v, visits, N);
  scan_blocksum<<<nbv, 256, 0, stream>>>(cnt_v, bsum, KVIS);
  scan_write<<<nbv, 256, 0, stream>>>(cnt_v, bsum, cur_v, KVIS);
  visit3_all<1><<<dim3(pb, 24), 256, 0, stream>>>(xyz_s, cnt_v, cur_v, visits, N);
  visit2_all<1><<<dim3(pb, 36), 256, 0, stream>>>(xy_g, cnt_v, cur_v, visits, N);

  // creates: one dispatch per homogeneous segment (balanced XCD swizzle)
  create_block<<<4096, 256, 0, stream>>>(feat_s, cnt_v, cur_v, visits, grid, KO16);
  create_block<<<32768, 256, 0, stream>>>(feat_s, cnt_v, cur_v, visits, grid, KO32);
  create_wave4<<<262144 / 4, 256, 0, stream>>>(feat_s, cnt_v, cur_v, visits, grid, KO64,
                                               262144);
  create_block<<<12288, 256, 0, stream>>>(feat_g, cnt_v, cur_v, visits, grid, KO64Q);
  create_block<<<49152, 256, 0, stream>>>(feat_g, cnt_v, cur_v, visits, grid, KO128Q);
  create_wave4<<<196608 / 4, 256, 0, stream>>>(feat_g, cnt_v, cur_v, visits, grid,
                                               KO256Q, 196608);

  // fused encode: all 12 slots in one dispatch
  encode_all<<<(M * 32 + 255) / 256, 256, 0, stream>>>(xyz_i, grid, out, M);
}

// Round 11
// 841.129 us; speedup vs baseline: 1.0989x; 1.0989x over previous
//
#include <hip/hip_runtime.h>

#define NF 32
#define EPSF 1e-9f

// concatenated keyspaces
// sort:  [0,262144) morton3@64 ; [262144 + g*65536) pair g morton2@256   (KSORT=458752)
// visit: R16 [0,4096) R32 [4096,36864) R64 [36864,299008)
//        64^2 [299008 + g*4096) 128^2 [311296 + g*16384) 256^2 [360448 + g*65536)  (KVIS=557056)
#define KSORT 458752
#define KVIS 557056
#define KO16 0
#define KO32 4096
#define KO64 36864
#define KO64Q 299008
#define KO128Q 311296
#define KO256Q 360448

__device__ __forceinline__ int cell_coord(float xv, int R, float& fr) {
  float x = xv * (float)(R - 1);
  int i0 = (int)floorf(x);
  i0 = min(max(i0, 0), R - 2);
  fr = x - (float)i0;
  return i0;
}
__device__ __forceinline__ float bf2f(unsigned short u) {
  return __uint_as_float((unsigned)u << 16);
}
__device__ __forceinline__ unsigned short f2bf(float x) {
  unsigned b = __float_as_uint(x);
  return (unsigned short)((b + 0x7FFF + ((b >> 16) & 1)) >> 16);
}
__device__ __forceinline__ unsigned p1b2(unsigned x) {
  x &= 0x3FF;
  x = (x | (x << 16)) & 0x030000FF;
  x = (x | (x << 8)) & 0x0300F00F;
  x = (x | (x << 4)) & 0x030C30C3;
  x = (x | (x << 2)) & 0x09249249;
  return x;
}
__device__ __forceinline__ unsigned p1b1(unsigned x) {
  x &= 0xFFFF;
  x = (x | (x << 8)) & 0x00FF00FF;
  x = (x | (x << 4)) & 0x0F0F0F0F;
  x = (x | (x << 2)) & 0x33333333;
  x = (x | (x << 1)) & 0x55555555;
  return x;
}

// XCD-aware bijective swizzle: contiguous chunk per XCD (requires n % 8 == 0)
__device__ __forceinline__ int xcd_swz(int bid, int n) {
  return (bid & 7) * (n >> 3) + (bid >> 3);
}

// ---- wave-aggregated atomics over sorted-ish keys ----
__device__ __forceinline__ void agg_hist(int key, int* cnt) {
  int lane = threadIdx.x & 63;
  unsigned long long amask = __ballot(1);
  int nact = __popcll(amask);
  int prev = __shfl_up(key, 1);
  bool leader = (lane == 0) || (prev != key);
  unsigned long long lmask = __ballot(leader);
  if (leader) {
    unsigned long long above = (lane < 63) ? (lmask >> (lane + 1)) : 0ULL;
    int next = above ? (lane + 1 + (__ffsll((unsigned long long)above) - 1)) : nact;
    atomicAdd(&cnt[key], next - lane);
  }
}
__device__ __forceinline__ int agg_place(int key, int* cur) {
  int lane = threadIdx.x & 63;
  unsigned long long amask = __ballot(1);
  int nact = __popcll(amask);
  int prev = __shfl_up(key, 1);
  bool leader = (lane == 0) || (prev != key);
  unsigned long long lmask = __ballot(leader);
  unsigned long long below = lmask & ((2ULL << lane) - 1ULL);
  int lp = 63 - __clzll((long long)below);
  int base = 0;
  if (leader) {
    unsigned long long above = (lane < 63) ? (lmask >> (lane + 1)) : 0ULL;
    int next = above ? (lane + 1 + (__ffsll((unsigned long long)above) - 1)) : nact;
    base = atomicAdd(&cur[key], next - lane);
  }
  base = __shfl(base, lp);
  return base + (lane - lp);
}

// ---------------- fused sort keys: morton3@64 + 3 pair keys@256 ----------------
__global__ __launch_bounds__(256) void sort_hist_all(
    const float* __restrict__ xyz, int* __restrict__ cnt, int N) {
  int p = blockIdx.x * blockDim.x + threadIdx.x;
  if (p >= N) return;
  float fr;
  int c64[3], c256[3];
#pragma unroll
  for (int d = 0; d < 3; ++d) {
    c64[d] = cell_coord(xyz[p * 3 + d], 64, fr);
    c256[d] = cell_coord(xyz[p * 3 + d], 256, fr);
  }
  int k3 = (int)((p1b2((unsigned)c64[0]) << 2) | (p1b2((unsigned)c64[1]) << 1) |
                 p1b2((unsigned)c64[2]));
  atomicAdd(&cnt[k3], 1);
#pragma unroll
  for (int g = 0; g < 3; ++g) {
    int a = (g < 2) ? 0 : 1, b = (g == 0) ? 1 : 2;
    int key = 262144 + g * 65536 +
              (int)((p1b1((unsigned)c256[a]) << 1) | p1b1((unsigned)c256[b]));
    atomicAdd(&cnt[key], 1);
  }
}
__global__ __launch_bounds__(256) void sort_place_all(
    const float* __restrict__ xyz, int* __restrict__ cur, int* __restrict__ perm, int N) {
  int p = blockIdx.x * blockDim.x + threadIdx.x;
  if (p >= N) return;
  float fr;
  int c64[3], c256[3];
#pragma unroll
  for (int d = 0; d < 3; ++d) {
    c64[d] = cell_coord(xyz[p * 3 + d], 64, fr);
    c256[d] = cell_coord(xyz[p * 3 + d], 256, fr);
  }
  int k3 = (int)((p1b2((unsigned)c64[0]) << 2) | (p1b2((unsigned)c64[1]) << 1) |
                 p1b2((unsigned)c64[2]));
  perm[atomicAdd(&cur[k3], 1)] = p;
#pragma unroll
  for (int g = 0; g < 3; ++g) {
    int a = (g < 2) ? 0 : 1, b = (g == 0) ? 1 : 2;
    int key = 262144 + g * 65536 +
              (int)((p1b1((unsigned)c256[a]) << 1) | p1b1((unsigned)c256[b]));
    perm[atomicAdd(&cur[key], 1)] = p;
  }
}
__global__ __launch_bounds__(256) void permute_all(
    const float* __restrict__ xyz, const float* __restrict__ feat,
    const int* __restrict__ perm, float* __restrict__ xyz_s,
    unsigned short* __restrict__ feat_s, float* __restrict__ xy_g,
    unsigned short* __restrict__ feat_g, int N) {
  int t = blockIdx.x * blockDim.x + threadIdx.x;
  int s = t >> 5, f = t & 31;
  if (s >= 4 * N) return;
  int q = perm[s];
  float v = feat[(size_t)q * NF + f];
  if (s < N) {
    feat_s[(size_t)s * NF + f] = f2bf(v);
    if (f < 3) xyz_s[s * 3 + f] = xyz[q * 3 + f];
  } else {
    int sl = s - N;
    int g = sl / N;
    feat_g[(size_t)sl * NF + f] = f2bf(v);
    if (f < 2) {
      int a = (g < 2) ? 0 : 1, b = (g == 0) ? 1 : 2;
      xy_g[(size_t)sl * 2 + f] = xyz[q * 3 + (f == 0 ? a : b)];
    }
  }
}

// ---------------- scan (hierarchical, exclusive) ----------------
__global__ __launch_bounds__(256) void scan_blocksum(
    const int* __restrict__ cnt, int* __restrict__ bsum, int K) {
  __shared__ int red[256];
  int base = blockIdx.x * 2048 + threadIdx.x * 8;
  int s = 0;
#pragma unroll
  for (int j = 0; j < 8; ++j) {
    int k = base + j;
    if (k < K) s += cnt[k];
  }
  red[threadIdx.x] = s;
  __syncthreads();
  for (int off = 128; off > 0; off >>= 1) {
    if (threadIdx.x < off) red[threadIdx.x] += red[threadIdx.x + off];
    __syncthreads();
  }
  if (threadIdx.x == 0) bsum[blockIdx.x] = red[0];
}
__global__ __launch_bounds__(256) void scan_write(
    const int* __restrict__ cnt, const int* __restrict__ bsum,
    int* __restrict__ cur, int K) {
  __shared__ int lds[256];
  __shared__ int boff;
  int b = blockIdx.x, t = threadIdx.x;
  if (t == 0) {
    int s = 0;
    for (int j = 0; j < b; ++j) s += bsum[j];
    boff = s;
  }
  int base = b * 2048 + t * 8;
  int v[8];
  int s = 0;
#pragma unroll
  for (int j = 0; j < 8; ++j) {
    int k = base + j;
    v[j] = (k < K) ? cnt[k] : 0;
    s += v[j];
  }
  lds[t] = s;
  __syncthreads();
  for (int off = 1; off < 256; off <<= 1) {
    int add = (t >= off) ? lds[t - off] : 0;
    __syncthreads();
    lds[t] += add;
    __syncthreads();
  }
  int run = boff + lds[t] - s;
#pragma unroll
  for (int j = 0; j < 8; ++j) {
    int k = base + j;
    if (k < K) {
      cur[k] = run;
      run += v[j];
    }
  }
}

// ---------------- visit emission: one resolution per blockIdx.y ----------------
template <int PHASE>
__global__ __launch_bounds__(256) void visit3_all(
    const float* __restrict__ xyz, int* __restrict__ cnt, int* __restrict__ cur,
    int2* __restrict__ visits, int N) {
  int r = blockIdx.y;  // 0..2
  int p = blockIdx.x * blockDim.x + threadIdx.x;
  if (p >= N) return;
  int R = 16 << r;
  int ko = (r == 0) ? KO16 : (r == 1 ? KO32 : KO64);
  unsigned a0[3], a1[3];
  float fr[3];
#pragma unroll
  for (int d = 0; d < 3; ++d) {
    int i0 = cell_coord(xyz[p * 3 + d], R, fr[d]);
    a0[d] = p1b2((unsigned)i0);
    a1[d] = p1b2((unsigned)(i0 + 1));
  }
#pragma unroll
  for (int cb = 0; cb < 8; ++cb) {
    float w = 1.f;
    unsigned key = 0;
#pragma unroll
    for (int d = 0; d < 3; ++d) {
      int o = (cb >> d) & 1;
      w *= o ? fr[d] : (1.f - fr[d]);
      key |= (o ? a1[d] : a0[d]) << (2 - d);
    }
    int k = ko + (int)key;
    if (PHASE == 0) {
      agg_hist(k, cnt);
    } else {
      int pos = agg_place(k, cur);
      visits[pos] = make_int2(p, __float_as_int(w));
    }
  }
}

// one (pair, resolution) per blockIdx.y
template <int PHASE>
__global__ __launch_bounds__(256) void visit2_all(
    const float* __restrict__ xy_g, int* __restrict__ cnt, int* __restrict__ cur,
    int2* __restrict__ visits, int N) {
  int y = blockIdx.y;  // 0..8 : g*3 + r
  int g = y / 3, r = y % 3;
  int p = blockIdx.x * blockDim.x + threadIdx.x;
  if (p >= N) return;
  int sl = g * N + p;
  int R = 64 << r;
  int kb = (r == 0) ? KO64Q : (r == 1 ? KO128Q : KO256Q);
  int base = kb + g * R * R;
  float frx, fry;
  int ix = cell_coord(xy_g[(size_t)sl * 2 + 0], R, frx);
  int iy = cell_coord(xy_g[(size_t)sl * 2 + 1], R, fry);
  unsigned ax0 = p1b1((unsigned)ix), ax1 = p1b1((unsigned)(ix + 1));
  unsigned ay0 = p1b1((unsigned)iy), ay1 = p1b1((unsigned)(iy + 1));
#pragma unroll
  for (int cb = 0; cb < 4; ++cb) {
    int o0 = (cb >> 1) & 1, o1 = cb & 1;
    float w = (o0 ? frx : 1.f - frx) * (o1 ? fry : 1.f - fry);
    int k = base + (int)(((o0 ? ax1 : ax0) << 1) | (o1 ? ay1 : ay0));
    if (PHASE == 0) {
      agg_hist(k, cnt);
    } else {
      int pos = agg_place(k, cur);
      visits[pos] = make_int2(sl, __float_as_int(w));
    }
  }
}

// ---------------- create: block-per-cell, 16 slots x 16 feat-pairs ----------------
__global__ __launch_bounds__(256) void create_block(
    const unsigned short* __restrict__ feat, const int* __restrict__ cnt,
    const int* __restrict__ cur_end, const int2* __restrict__ visits,
    unsigned short* __restrict__ grid, int CBASE) {
  __shared__ int2 vlds[1024];
  __shared__ float2 lacc[256];
  __shared__ float lw[16];
  int cell = CBASE + xcd_swz(blockIdx.x, gridDim.x);
  int e = cur_end[cell];
  int n = cnt[cell];
  int beg = e - n;
  for (int i = threadIdx.x; i < n && i < 1024; i += 256) vlds[i] = visits[beg + i];
  __syncthreads();
  bool inl = (n <= 1024);
  int slot = threadIdx.x >> 4;  // 0..15
  int fp = threadIdx.x & 15;    // feature pair
  float2 acc = {0.f, 0.f};
  float wsum = 0.f;
  int i = slot;
  for (; i + 16 < n; i += 32) {
    int2 v0 = inl ? vlds[i] : visits[beg + i];
    int2 v1 = inl ? vlds[i + 16] : visits[beg + i + 16];
    unsigned u0 = *(const unsigned*)(feat + (size_t)v0.x * NF + 2 * fp);
    unsigned u1 = *(const unsigned*)(feat + (size_t)v1.x * NF + 2 * fp);
    float w0 = __int_as_float(v0.y), w1 = __int_as_float(v1.y);
    acc.x = fmaf(w0, bf2f((unsigned short)u0), acc.x);
    acc.y = fmaf(w0, bf2f((unsigned short)(u0 >> 16)), acc.y);
    acc.x = fmaf(w1, bf2f((unsigned short)u1), acc.x);
    acc.y = fmaf(w1, bf2f((unsigned short)(u1 >> 16)), acc.y);
    wsum += w0 + w1;
  }
  if (i < n) {
    int2 v = inl ? vlds[i] : visits[beg + i];
    unsigned u = *(const unsigned*)(feat + (size_t)v.x * NF + 2 * fp);
    float w = __int_as_float(v.y);
    acc.x = fmaf(w, bf2f((unsigned short)u), acc.x);
    acc.y = fmaf(w, bf2f((unsigned short)(u >> 16)), acc.y);
    wsum += w;
  }
  lacc[threadIdx.x] = acc;
  if (fp == 0) lw[slot] = wsum;
  __syncthreads();
  if (threadIdx.x < 16) {
    float2 a = {0.f, 0.f};
    float w = 0.f;
#pragma unroll
    for (int s = 0; s < 16; ++s) {
      float2 t = lacc[s * 16 + threadIdx.x];
      a.x += t.x;
      a.y += t.y;
      w += lw[s];
    }
    float inv = 1.f / fmaxf(w, EPSF);
    unsigned short lo = f2bf(a.x * inv), hi = f2bf(a.y * inv);
    *(unsigned*)(grid + (size_t)cell * NF + 2 * threadIdx.x) =
        (unsigned)lo | ((unsigned)hi << 16);
  }
}

// ---------------- create: wave-per-cell (4/block), 4 slots x 16 feat-pairs ----------------
__global__ __launch_bounds__(256) void create_wave4(
    const unsigned short* __restrict__ feat, const int* __restrict__ cnt,
    const int* __restrict__ cur_end, const int2* __restrict__ visits,
    unsigned short* __restrict__ grid, int CBASE, int K) {
  __shared__ int2 vlds[1024];
  int wave = threadIdx.x >> 6, lane = threadIdx.x & 63;
  int slot = lane >> 4;  // 0..3
  int fp = lane & 15;
  int c0 = CBASE + xcd_swz(blockIdx.x, gridDim.x) * 4;
  int lastc = min(c0 + 3, CBASE + K - 1);
  int vbase = cur_end[c0] - cnt[c0];
  int vlen = cur_end[lastc] - vbase;
  for (int i = threadIdx.x; i < vlen && i < 1024; i += 256) vlds[i] = visits[vbase + i];
  __syncthreads();
  int cell = c0 + wave;
  if (cell > lastc) return;
  int e = cur_end[cell];
  int n = cnt[cell];
  int beg = e - n;
  bool inl = (e - vbase) <= 1024;
  int b0 = beg - vbase;
  float2 acc = {0.f, 0.f};
  float wsum = 0.f;
  for (int i = slot; i < n; i += 4) {
    int2 v = inl ? vlds[b0 + i] : visits[beg + i];
    unsigned u = *(const unsigned*)(feat + (size_t)v.x * NF + 2 * fp);
    float w = __int_as_float(v.y);
    acc.x = fmaf(w, bf2f((unsigned short)u), acc.x);
    acc.y = fmaf(w, bf2f((unsigned short)(u >> 16)), acc.y);
    wsum += w;
  }
  acc.x += __shfl_xor(acc.x, 16);
  acc.y += __shfl_xor(acc.y, 16);
  wsum += __shfl_xor(wsum, 16);
  acc.x += __shfl_xor(acc.x, 32);
  acc.y += __shfl_xor(acc.y, 32);
  wsum += __shfl_xor(wsum, 32);
  if (slot == 0) {
    float inv = 1.f / fmaxf(wsum, EPSF);
    unsigned short lo = f2bf(acc.x * inv), hi = f2bf(acc.y * inv);
    *(unsigned*)(grid + (size_t)cell * NF + 2 * fp) =
        (unsigned)lo | ((unsigned)hi << 16);
  }
}

// ---------------- fused encode: all 12 slots ----------------
__global__ __launch_bounds__(256) void encode_all(
    const float* __restrict__ xyz, const unsigned short* __restrict__ grid,
    float* __restrict__ out, int M) {
  int t = blockIdx.x * blockDim.x + threadIdx.x;
  int m = t >> 5, f = t & 31;
  if (m >= M) return;
  float X[3];
#pragma unroll
  for (int d = 0; d < 3; ++d) X[d] = xyz[m * 3 + d];
  // 3D slots 0..2
  {
    const int RS[3] = {16, 32, 64};
    const int KO[3] = {KO16, KO32, KO64};
#pragma unroll
    for (int r = 0; r < 3; ++r) {
      unsigned a0[3], a1[3];
      float fr[3];
#pragma unroll
      for (int d = 0; d < 3; ++d) {
        int i0 = cell_coord(X[d], RS[r], fr[d]);
        a0[d] = p1b2((unsigned)i0);
        a1[d] = p1b2((unsigned)(i0 + 1));
      }
      float acc = 0.f;
#pragma unroll
      for (int cb = 0; cb < 8; ++cb) {
        float w = 1.f;
        unsigned key = 0;
#pragma unroll
        for (int d = 0; d < 3; ++d) {
          int o = (cb >> d) & 1;
          w *= o ? fr[d] : (1.f - fr[d]);
          key |= (o ? a1[d] : a0[d]) << (2 - d);
        }
        acc = fmaf(w, bf2f(grid[(size_t)(KO[r] + (int)key) * NF + f]), acc);
      }
      out[(size_t)m * 384 + r * 32 + f] = acc;
    }
  }
  // 2D slots 3..11
  {
    const int RS[3] = {64, 128, 256};
    const int KB[3] = {KO64Q, KO128Q, KO256Q};
    const int RSQ[3] = {4096, 16384, 65536};
#pragma unroll
    for (int r = 0; r < 3; ++r) {
      unsigned b0[3], b1[3];
      float fr[3];
#pragma unroll
      for (int d = 0; d < 3; ++d) {
        int i0 = cell_coord(X[d], RS[r], fr[d]);
        b0[d] = p1b1((unsigned)i0);
        b1[d] = p1b1((unsigned)(i0 + 1));
      }
#pragma unroll
      for (int g = 0; g < 3; ++g) {
        int a = (g < 2) ? 0 : 1, b = (g == 0) ? 1 : 2;
        int base = KB[r] + g * RSQ[r];
        float acc = 0.f;
#pragma unroll
        for (int cb = 0; cb < 4; ++cb) {
          int o0 = (cb >> 1) & 1, o1 = cb & 1;
          float w = (o0 ? fr[a] : 1.f - fr[a]) * (o1 ? fr[b] : 1.f - fr[b]);
          int k = base + (int)(((o0 ? b1[a] : b0[a]) << 1) | (o1 ? b1[b] : b0[b]));
          acc = fmaf(w, bf2f(grid[(size_t)k * NF + f]), acc);
        }
        out[(size_t)m * 384 + (3 + g * 3 + r) * 32 + f] = acc;
      }
    }
  }
}

extern "C" void kernel_launch(void* const* d_in, const int* in_sizes, int n_in,
                              void* d_out, int out_size, void* d_ws, size_t ws_size,
                              hipStream_t stream) {
  const float* xyz_c = (const float*)d_in[0];
  const float* xyz_i = (const float*)d_in[1];
  const float* feat = (const float*)d_in[2];
  float* out = (float*)d_out;
  int N = in_sizes[0] / 3;
  int M = in_sizes[1] / 3;

  char* wsb = (char*)d_ws;
  size_t off = 0;
  auto al = [&](size_t bytes) {
    size_t o = off;
    off = (off + bytes + 255) & ~(size_t)255;
    return wsb + o;
  };
  const int KALL = KSORT + KVIS;
  int* cnt_all = (int*)al((size_t)KALL * 4);
  int* cur_all = (int*)al((size_t)KALL * 4);
  int* bsum = (int*)al(4096);
  int* perm = (int*)al((size_t)4 * N * 4);
  float* xyz_s = (float*)al((size_t)N * 3 * 4);
  unsigned short* feat_s = (unsigned short*)al((size_t)N * NF * 2);
  float* xy_g = (float*)al((size_t)3 * N * 2 * 4);
  unsigned short* feat_g = (unsigned short*)al((size_t)3 * N * NF * 2);
  int2* visits = (int2*)al((size_t)60 * N * 8);
  unsigned short* grid = (unsigned short*)al((size_t)KVIS * NF * 2);

  int* cnt_v = cnt_all + KSORT;
  int* cur_v = cur_all + KSORT;

  int pb = (N + 255) / 256;
  int nbs = (KSORT + 2047) / 2048;
  int nbv = (KVIS + 2047) / 2048;

  hipMemsetAsync(cnt_all, 0, (size_t)KALL * 4, stream);

  // fused sort of all 4 point-orderings
  sort_hist_all<<<pb, 256, 0, stream>>>(xyz_c, cnt_all, N);
  scan_blocksum<<<nbs, 256, 0, stream>>>(cnt_all, bsum, KSORT);
  scan_write<<<nbs, 256, 0, stream>>>(cnt_all, bsum, cur_all, KSORT);
  sort_place_all<<<pb, 256, 0, stream>>>(xyz_c, cur_all, perm, N);
  permute_all<<<(4 * N * 32 + 255) / 256, 256, 0, stream>>>(xyz_c, feat, perm, xyz_s,
                                                            feat_s, xy_g, feat_g, N);

  // visit emission: one resolution (or pair,res) per blockIdx.y
  visit3_all<0><<<dim3(pb, 3), 256, 0, stream>>>(xyz_s, cnt_v, cur_v, visits, N);
  visit2_all<0><<<dim3(pb, 9), 256, 0, stream>>>(xy_g, cnt_v, cur_v, visits, N);
  scan_blocksum<<<nbv, 256, 0, stream>>>(cnt_v, bsum, KVIS);
  scan_write<<<nbv, 256, 0, stream>>>(cnt_v, bsum, cur_v, KVIS);
  visit3_all<1><<<dim3(pb, 3), 256, 0, stream>>>(xyz_s, cnt_v, cur_v, visits, N);
  visit2_all<1><<<dim3(pb, 9), 256, 0, stream>>>(xy_g, cnt_v, cur_v, visits, N);

  // creates: one dispatch per homogeneous segment (balanced XCD swizzle)
  create_block<<<4096, 256, 0, stream>>>(feat_s, cnt_v, cur_v, visits, grid, KO16);
  create_block<<<32768, 256, 0, stream>>>(feat_s, cnt_v, cur_v, visits, grid, KO32);
  create_wave4<<<262144 / 4, 256, 0, stream>>>(feat_s, cnt_v, cur_v, visits, grid, KO64,
                                               262144);
  create_block<<<12288, 256, 0, stream>>>(feat_g, cnt_v, cur_v, visits, grid, KO64Q);
  create_block<<<49152, 256, 0, stream>>>(feat_g, cnt_v, cur_v, visits, grid, KO128Q);
  create_wave4<<<196608 / 4, 256, 0, stream>>>(feat_g, cnt_v, cur_v, visits, grid,
                                               KO256Q, 196608);

  // fused encode: all 12 slots in one dispatch
  encode_all<<<(M * 32 + 255) / 256, 256, 0, stream>>>(xyz_i, grid, out, M);
}

// Round 12
// 839.245 us; speedup vs baseline: 1.1014x; 1.0022x over previous
//
#include <hip/hip_runtime.h>

#define NF 32
#define EPSF 1e-9f

// concatenated keyspaces
// sort:  [0,262144) morton3@64 ; [262144 + g*65536) pair g morton2@256   (KSORT=458752)
// visit: R16 [0,4096) R32 [4096,36864) R64 [36864,299008)
//        64^2 [299008 + g*4096) 128^2 [311296 + g*16384) 256^2 [360448 + g*65536)  (KVIS=557056)
#define KSORT 458752
#define KVIS 557056
#define KO16 0
#define KO32 4096
#define KO64 36864
#define KO64Q 299008
#define KO128Q 311296
#define KO256Q 360448

__device__ __forceinline__ int cell_coord(float xv, int R, float& fr) {
  float x = xv * (float)(R - 1);
  int i0 = (int)floorf(x);
  i0 = min(max(i0, 0), R - 2);
  fr = x - (float)i0;
  return i0;
}
__device__ __forceinline__ float bf2f(unsigned short u) {
  return __uint_as_float((unsigned)u << 16);
}
__device__ __forceinline__ unsigned short f2bf(float x) {
  unsigned b = __float_as_uint(x);
  return (unsigned short)((b + 0x7FFF + ((b >> 16) & 1)) >> 16);
}
__device__ __forceinline__ unsigned p1b2(unsigned x) {
  x &= 0x3FF;
  x = (x | (x << 16)) & 0x030000FF;
  x = (x | (x << 8)) & 0x0300F00F;
  x = (x | (x << 4)) & 0x030C30C3;
  x = (x | (x << 2)) & 0x09249249;
  return x;
}
__device__ __forceinline__ unsigned p1b1(unsigned x) {
  x &= 0xFFFF;
  x = (x | (x << 8)) & 0x00FF00FF;
  x = (x | (x << 4)) & 0x0F0F0F0F;
  x = (x | (x << 2)) & 0x33333333;
  x = (x | (x << 1)) & 0x55555555;
  return x;
}

// XCD-aware bijective swizzle: contiguous chunk per XCD (requires n % 8 == 0)
__device__ __forceinline__ int xcd_swz(int bid, int n) {
  return (bid & 7) * (n >> 3) + (bid >> 3);
}

// ---- wave-aggregated atomics over sorted-ish keys ----
__device__ __forceinline__ void agg_hist(int key, int* cnt) {
  int lane = threadIdx.x & 63;
  unsigned long long amask = __ballot(1);
  int nact = __popcll(amask);
  int prev = __shfl_up(key, 1);
  bool leader = (lane == 0) || (prev != key);
  unsigned long long lmask = __ballot(leader);
  if (leader) {
    unsigned long long above = (lane < 63) ? (lmask >> (lane + 1)) : 0ULL;
    int next = above ? (lane + 1 + (__ffsll((unsigned long long)above) - 1)) : nact;
    atomicAdd(&cnt[key], next - lane);
  }
}

// batched: phase A issues all NC atomics (results parked), phase B broadcasts.
template <int NC>
__device__ __forceinline__ void agg_place_batch(const int (&key)[NC], int* cur,
                                                int (&pos)[NC]) {
  int lane = threadIdx.x & 63;
  unsigned long long amask = __ballot(1);
  int nact = __popcll(amask);
  int ret[NC];
  int lp[NC];
#pragma unroll
  for (int c = 0; c < NC; ++c) {
    int prev = __shfl_up(key[c], 1);
    bool leader = (lane == 0) || (prev != key[c]);
    unsigned long long lmask = __ballot(leader);
    unsigned long long below = lmask & ((2ULL << lane) - 1ULL);
    lp[c] = 63 - __clzll((long long)below);
    ret[c] = 0;
    if (leader) {
      unsigned long long above = (lane < 63) ? (lmask >> (lane + 1)) : 0ULL;
      int next = above ? (lane + 1 + (__ffsll((unsigned long long)above) - 1)) : nact;
      ret[c] = atomicAdd(&cur[key[c]], next - lane);
    }
  }
#pragma unroll
  for (int c = 0; c < NC; ++c) {
    pos[c] = __shfl(ret[c], lp[c]) + (lane - lp[c]);
  }
}

// ---------------- fused sort keys: morton3@64 + 3 pair keys@256 ----------------
__global__ __launch_bounds__(256) void sort_hist_all(
    const float* __restrict__ xyz, int* __restrict__ cnt, int N) {
  int p = blockIdx.x * blockDim.x + threadIdx.x;
  if (p >= N) return;
  float fr;
  int c64[3], c256[3];
#pragma unroll
  for (int d = 0; d < 3; ++d) {
    c64[d] = cell_coord(xyz[p * 3 + d], 64, fr);
    c256[d] = cell_coord(xyz[p * 3 + d], 256, fr);
  }
  int k3 = (int)((p1b2((unsigned)c64[0]) << 2) | (p1b2((unsigned)c64[1]) << 1) |
                 p1b2((unsigned)c64[2]));
  atomicAdd(&cnt[k3], 1);
#pragma unroll
  for (int g = 0; g < 3; ++g) {
    int a = (g < 2) ? 0 : 1, b = (g == 0) ? 1 : 2;
    int key = 262144 + g * 65536 +
              (int)((p1b1((unsigned)c256[a]) << 1) | p1b1((unsigned)c256[b]));
    atomicAdd(&cnt[key], 1);
  }
}
__global__ __launch_bounds__(256) void sort_place_all(
    const float* __restrict__ xyz, int* __restrict__ cur, int* __restrict__ perm, int N) {
  int p = blockIdx.x * blockDim.x + threadIdx.x;
  if (p >= N) return;
  float fr;
  int c64[3], c256[3];
#pragma unroll
  for (int d = 0; d < 3; ++d) {
    c64[d] = cell_coord(xyz[p * 3 + d], 64, fr);
    c256[d] = cell_coord(xyz[p * 3 + d], 256, fr);
  }
  int k3 = (int)((p1b2((unsigned)c64[0]) << 2) | (p1b2((unsigned)c64[1]) << 1) |
                 p1b2((unsigned)c64[2]));
  perm[atomicAdd(&cur[k3], 1)] = p;
#pragma unroll
  for (int g = 0; g < 3; ++g) {
    int a = (g < 2) ? 0 : 1, b = (g == 0) ? 1 : 2;
    int key = 262144 + g * 65536 +
              (int)((p1b1((unsigned)c256[a]) << 1) | p1b1((unsigned)c256[b]));
    perm[atomicAdd(&cur[key], 1)] = p;
  }
}
__global__ __launch_bounds__(256) void permute_all(
    const float* __restrict__ xyz, const float* __restrict__ feat,
    const int* __restrict__ perm, float* __restrict__ xyz_s,
    unsigned short* __restrict__ feat_s, float* __restrict__ xy_g,
    unsigned short* __restrict__ feat_g, int N) {
  int t = blockIdx.x * blockDim.x + threadIdx.x;
  int s = t >> 5, f = t & 31;
  if (s >= 4 * N) return;
  int q = perm[s];
  float v = feat[(size_t)q * NF + f];
  if (s < N) {
    feat_s[(size_t)s * NF + f] = f2bf(v);
    if (f < 3) xyz_s[s * 3 + f] = xyz[q * 3 + f];
  } else {
    int sl = s - N;
    int g = sl / N;
    feat_g[(size_t)sl * NF + f] = f2bf(v);
    if (f < 2) {
      int a = (g < 2) ? 0 : 1, b = (g == 0) ? 1 : 2;
      xy_g[(size_t)sl * 2 + f] = xyz[q * 3 + (f == 0 ? a : b)];
    }
  }
}

// ---------------- scan (hierarchical, exclusive) ----------------
__global__ __launch_bounds__(256) void scan_blocksum(
    const int* __restrict__ cnt, int* __restrict__ bsum, int K) {
  __shared__ int red[256];
  int base = blockIdx.x * 2048 + threadIdx.x * 8;
  int s = 0;
#pragma unroll
  for (int j = 0; j < 8; ++j) {
    int k = base + j;
    if (k < K) s += cnt[k];
  }
  red[threadIdx.x] = s;
  __syncthreads();
  for (int off = 128; off > 0; off >>= 1) {
    if (threadIdx.x < off) red[threadIdx.x] += red[threadIdx.x + off];
    __syncthreads();
  }
  if (threadIdx.x == 0) bsum[blockIdx.x] = red[0];
}
__global__ __launch_bounds__(256) void scan_write(
    const int* __restrict__ cnt, const int* __restrict__ bsum,
    int* __restrict__ cur, int K) {
  __shared__ int lds[256];
  __shared__ int boff;
  int b = blockIdx.x, t = threadIdx.x;
  if (t == 0) {
    int s = 0;
    for (int j = 0; j < b; ++j) s += bsum[j];
    boff = s;
  }
  int base = b * 2048 + t * 8;
  int v[8];
  int s = 0;
#pragma unroll
  for (int j = 0; j < 8; ++j) {
    int k = base + j;
    v[j] = (k < K) ? cnt[k] : 0;
    s += v[j];
  }
  lds[t] = s;
  __syncthreads();
  for (int off = 1; off < 256; off <<= 1) {
    int add = (t >= off) ? lds[t - off] : 0;
    __syncthreads();
    lds[t] += add;
    __syncthreads();
  }
  int run = boff + lds[t] - s;
#pragma unroll
  for (int j = 0; j < 8; ++j) {
    int k = base + j;
    if (k < K) {
      cur[k] = run;
      run += v[j];
    }
  }
}

// ---------------- visit emission: one resolution per blockIdx.y ----------------
template <int PHASE>
__global__ __launch_bounds__(256) void visit3_all(
    const float* __restrict__ xyz, int* __restrict__ cnt, int* __restrict__ cur,
    int2* __restrict__ visits, int N) {
  int r = blockIdx.y;  // 0..2
  int p = blockIdx.x * blockDim.x + threadIdx.x;
  if (p >= N) return;
  int R = 16 << r;
  int ko = (r == 0) ? KO16 : (r == 1 ? KO32 : KO64);
  unsigned a0[3], a1[3];
  float fr[3];
#pragma unroll
  for (int d = 0; d < 3; ++d) {
    int i0 = cell_coord(xyz[p * 3 + d], R, fr[d]);
    a0[d] = p1b2((unsigned)i0);
    a1[d] = p1b2((unsigned)(i0 + 1));
  }
  int keys[8];
  float ws[8];
#pragma unroll
  for (int cb = 0; cb < 8; ++cb) {
    float w = 1.f;
    unsigned key = 0;
#pragma unroll
    for (int d = 0; d < 3; ++d) {
      int o = (cb >> d) & 1;
      w *= o ? fr[d] : (1.f - fr[d]);
      key |= (o ? a1[d] : a0[d]) << (2 - d);
    }
    keys[cb] = ko + (int)key;
    ws[cb] = w;
  }
  if (PHASE == 0) {
#pragma unroll
    for (int cb = 0; cb < 8; ++cb) agg_hist(keys[cb], cnt);
  } else {
    int pos[8];
    agg_place_batch<8>(keys, cur, pos);
#pragma unroll
    for (int cb = 0; cb < 8; ++cb)
      visits[pos[cb]] = make_int2(p, __float_as_int(ws[cb]));
  }
}

// one (pair, resolution) per blockIdx.y
template <int PHASE>
__global__ __launch_bounds__(256) void visit2_all(
    const float* __restrict__ xy_g, int* __restrict__ cnt, int* __restrict__ cur,
    int2* __restrict__ visits, int N) {
  int y = blockIdx.y;  // 0..8 : g*3 + r
  int g = y / 3, r = y % 3;
  int p = blockIdx.x * blockDim.x + threadIdx.x;
  if (p >= N) return;
  int sl = g * N + p;
  int R = 64 << r;
  int kb = (r == 0) ? KO64Q : (r == 1 ? KO128Q : KO256Q);
  int base = kb + g * R * R;
  float frx, fry;
  int ix = cell_coord(xy_g[(size_t)sl * 2 + 0], R, frx);
  int iy = cell_coord(xy_g[(size_t)sl * 2 + 1], R, fry);
  unsigned ax0 = p1b1((unsigned)ix), ax1 = p1b1((unsigned)(ix + 1));
  unsigned ay0 = p1b1((unsigned)iy), ay1 = p1b1((unsigned)(iy + 1));
  int keys[4];
  float ws[4];
#pragma unroll
  for (int cb = 0; cb < 4; ++cb) {
    int o0 = (cb >> 1) & 1, o1 = cb & 1;
    ws[cb] = (o0 ? frx : 1.f - frx) * (o1 ? fry : 1.f - fry);
    keys[cb] = base + (int)(((o0 ? ax1 : ax0) << 1) | (o1 ? ay1 : ay0));
  }
  if (PHASE == 0) {
#pragma unroll
    for (int cb = 0; cb < 4; ++cb) agg_hist(keys[cb], cnt);
  } else {
    int pos[4];
    agg_place_batch<4>(keys, cur, pos);
#pragma unroll
    for (int cb = 0; cb < 4; ++cb)
      visits[pos[cb]] = make_int2(sl, __float_as_int(ws[cb]));
  }
}

// ---------------- create: block-per-cell, 16 slots x 16 feat-pairs ----------------
__global__ __launch_bounds__(256) void create_block(
    const unsigned short* __restrict__ feat, const int* __restrict__ cnt,
    const int* __restrict__ cur_end, const int2* __restrict__ visits,
    unsigned short* __restrict__ grid, int CBASE) {
  __shared__ int2 vlds[1024];
  __shared__ float2 lacc[256];
  __shared__ float lw[16];
  int cell = CBASE + xcd_swz(blockIdx.x, gridDim.x);
  int e = cur_end[cell];
  int n = cnt[cell];
  int beg = e - n;
  for (int i = threadIdx.x; i < n && i < 1024; i += 256) vlds[i] = visits[beg + i];
  __syncthreads();
  bool inl = (n <= 1024);
  int slot = threadIdx.x >> 4;  // 0..15
  int fp = threadIdx.x & 15;    // feature pair
  float2 acc = {0.f, 0.f};
  float wsum = 0.f;
  int i = slot;
  for (; i + 16 < n; i += 32) {
    int2 v0 = inl ? vlds[i] : visits[beg + i];
    int2 v1 = inl ? vlds[i + 16] : visits[beg + i + 16];
    unsigned u0 = *(const unsigned*)(feat + (size_t)v0.x * NF + 2 * fp);
    unsigned u1 = *(const unsigned*)(feat + (size_t)v1.x * NF + 2 * fp);
    float w0 = __int_as_float(v0.y), w1 = __int_as_float(v1.y);
    acc.x = fmaf(w0, bf2f((unsigned short)u0), acc.x);
    acc.y = fmaf(w0, bf2f((unsigned short)(u0 >> 16)), acc.y);
    acc.x = fmaf(w1, bf2f((unsigned short)u1), acc.x);
    acc.y = fmaf(w1, bf2f((unsigned short)(u1 >> 16)), acc.y);
    wsum += w0 + w1;
  }
  if (i < n) {
    int2 v = inl ? vlds[i] : visits[beg + i];
    unsigned u = *(const unsigned*)(feat + (size_t)v.x * NF + 2 * fp);
    float w = __int_as_float(v.y);
    acc.x = fmaf(w, bf2f((unsigned short)u), acc.x);
    acc.y = fmaf(w, bf2f((unsigned short)(u >> 16)), acc.y);
    wsum += w;
  }
  lacc[threadIdx.x] = acc;
  if (fp == 0) lw[slot] = wsum;
  __syncthreads();
  if (threadIdx.x < 16) {
    float2 a = {0.f, 0.f};
    float w = 0.f;
#pragma unroll
    for (int s = 0; s < 16; ++s) {
      float2 t = lacc[s * 16 + threadIdx.x];
      a.x += t.x;
      a.y += t.y;
      w += lw[s];
    }
    float inv = 1.f / fmaxf(w, EPSF);
    unsigned short lo = f2bf(a.x * inv), hi = f2bf(a.y * inv);
    *(unsigned*)(grid + (size_t)cell * NF + 2 * threadIdx.x) =
        (unsigned)lo | ((unsigned)hi << 16);
  }
}

// ---------------- create: wave-per-cell (4/block), 4 slots x 16 feat-pairs ----------------
__global__ __launch_bounds__(256) void create_wave4(
    const unsigned short* __restrict__ feat, const int* __restrict__ cnt,
    const int* __restrict__ cur_end, const int2* __restrict__ visits,
    unsigned short* __restrict__ grid, int CBASE, int K) {
  __shared__ int2 vlds[1024];
  int wave = threadIdx.x >> 6, lane = threadIdx.x & 63;
  int slot = lane >> 4;  // 0..3
  int fp = lane & 15;
  int c0 = CBASE + xcd_swz(blockIdx.x, gridDim.x) * 4;
  int lastc = min(c0 + 3, CBASE + K - 1);
  int vbase = cur_end[c0] - cnt[c0];
  int vlen = cur_end[lastc] - vbase;
  for (int i = threadIdx.x; i < vlen && i < 1024; i += 256) vlds[i] = visits[vbase + i];
  __syncthreads();
  int cell = c0 + wave;
  if (cell > lastc) return;
  int e = cur_end[cell];
  int n = cnt[cell];
  int beg = e - n;
  bool inl = (e - vbase) <= 1024;
  int b0 = beg - vbase;
  float2 acc = {0.f, 0.f};
  float wsum = 0.f;
  for (int i = slot; i < n; i += 4) {
    int2 v = inl ? vlds[b0 + i] : visits[beg + i];
    unsigned u = *(const unsigned*)(feat + (size_t)v.x * NF + 2 * fp);
    float w = __int_as_float(v.y);
    acc.x = fmaf(w, bf2f((unsigned short)u), acc.x);
    acc.y = fmaf(w, bf2f((unsigned short)(u >> 16)), acc.y);
    wsum += w;
  }
  acc.x += __shfl_xor(acc.x, 16);
  acc.y += __shfl_xor(acc.y, 16);
  wsum += __shfl_xor(wsum, 16);
  acc.x += __shfl_xor(acc.x, 32);
  acc.y += __shfl_xor(acc.y, 32);
  wsum += __shfl_xor(wsum, 32);
  if (slot == 0) {
    float inv = 1.f / fmaxf(wsum, EPSF);
    unsigned short lo = f2bf(acc.x * inv), hi = f2bf(acc.y * inv);
    *(unsigned*)(grid + (size_t)cell * NF + 2 * fp) =
        (unsigned)lo | ((unsigned)hi << 16);
  }
}

// ---------------- fused encode: all 12 slots ----------------
__global__ __launch_bounds__(256) void encode_all(
    const float* __restrict__ xyz, const unsigned short* __restrict__ grid,
    float* __restrict__ out, int M) {
  int t = blockIdx.x * blockDim.x + threadIdx.x;
  int m = t >> 5, f = t & 31;
  if (m >= M) return;
  float X[3];
#pragma unroll
  for (int d = 0; d < 3; ++d) X[d] = xyz[m * 3 + d];
  // 3D slots 0..2
  {
    const int RS[3] = {16, 32, 64};
    const int KO[3] = {KO16, KO32, KO64};
#pragma unroll
    for (int r = 0; r < 3; ++r) {
      unsigned a0[3], a1[3];
      float fr[3];
#pragma unroll
      for (int d = 0; d < 3; ++d) {
        int i0 = cell_coord(X[d], RS[r], fr[d]);
        a0[d] = p1b2((unsigned)i0);
        a1[d] = p1b2((unsigned)(i0 + 1));
      }
      float acc = 0.f;
#pragma unroll
      for (int cb = 0; cb < 8; ++cb) {
        float w = 1.f;
        unsigned key = 0;
#pragma unroll
        for (int d = 0; d < 3; ++d) {
          int o = (cb >> d) & 1;
          w *= o ? fr[d] : (1.f - fr[d]);
          key |= (o ? a1[d] : a0[d]) << (2 - d);
        }
        acc = fmaf(w, bf2f(grid[(size_t)(KO[r] + (int)key) * NF + f]), acc);
      }
      out[(size_t)m * 384 + r * 32 + f] = acc;
    }
  }
  // 2D slots 3..11
  {
    const int RS[3] = {64, 128, 256};
    const int KB[3] = {KO64Q, KO128Q, KO256Q};
    const int RSQ[3] = {4096, 16384, 65536};
#pragma unroll
    for (int r = 0; r < 3; ++r) {
      unsigned b0[3], b1[3];
      float fr[3];
#pragma unroll
      for (int d = 0; d < 3; ++d) {
        int i0 = cell_coord(X[d], RS[r], fr[d]);
        b0[d] = p1b1((unsigned)i0);
        b1[d] = p1b1((unsigned)(i0 + 1));
      }
#pragma unroll
      for (int g = 0; g < 3; ++g) {
        int a = (g < 2) ? 0 : 1, b = (g == 0) ? 1 : 2;
        int base = KB[r] + g * RSQ[r];
        float acc = 0.f;
#pragma unroll
        for (int cb = 0; cb < 4; ++cb) {
          int o0 = (cb >> 1) & 1, o1 = cb & 1;
          float w = (o0 ? fr[a] : 1.f - fr[a]) * (o1 ? fr[b] : 1.f - fr[b]);
          int k = base + (int)(((o0 ? b1[a] : b0[a]) << 1) | (o1 ? b1[b] : b0[b]));
          acc = fmaf(w, bf2f(grid[(size_t)k * NF + f]), acc);
        }
        out[(size_t)m * 384 + (3 + g * 3 + r) * 32 + f] = acc;
      }
    }
  }
}

extern "C" void kernel_launch(void* const* d_in, const int* in_sizes, int n_in,
                              void* d_out, int out_size, void* d_ws, size_t ws_size,
                              hipStream_t stream) {
  const float* xyz_c = (const float*)d_in[0];
  const float* xyz_i = (const float*)d_in[1];
  const float* feat = (const float*)d_in[2];
  float* out = (float*)d_out;
  int N = in_sizes[0] / 3;
  int M = in_sizes[1] / 3;

  char* wsb = (char*)d_ws;
  size_t off = 0;
  auto al = [&](size_t bytes) {
    size_t o = off;
    off = (off + bytes + 255) & ~(size_t)255;
    return wsb + o;
  };
  const int KALL = KSORT + KVIS;
  int* cnt_all = (int*)al((size_t)KALL * 4);
  int* cur_all = (int*)al((size_t)KALL * 4);
  int* bsum = (int*)al(4096);
  int* perm = (int*)al((size_t)4 * N * 4);
  float* xyz_s = (float*)al((size_t)N * 3 * 4);
  unsigned short* feat_s = (unsigned short*)al((size_t)N * NF * 2);
  float* xy_g = (float*)al((size_t)3 * N * 2 * 4);
  unsigned short* feat_g = (unsigned short*)al((size_t)3 * N * NF * 2);
  int2* visits = (int2*)al((size_t)60 * N * 8);
  unsigned short* grid = (unsigned short*)al((size_t)KVIS * NF * 2);

  int* cnt_v = cnt_all + KSORT;
  int* cur_v = cur_all + KSORT;

  int pb = (N + 255) / 256;
  int nbs = (KSORT + 2047) / 2048;
  int nbv = (KVIS + 2047) / 2048;

  hipMemsetAsync(cnt_all, 0, (size_t)KALL * 4, stream);

  // fused sort of all 4 point-orderings
  sort_hist_all<<<pb, 256, 0, stream>>>(xyz_c, cnt_all, N);
  scan_blocksum<<<nbs, 256, 0, stream>>>(cnt_all, bsum, KSORT);
  scan_write<<<nbs, 256, 0, stream>>>(cnt_all, bsum, cur_all, KSORT);
  sort_place_all<<<pb, 256, 0, stream>>>(xyz_c, cur_all, perm, N);
  permute_all<<<(4 * N * 32 + 255) / 256, 256, 0, stream>>>(xyz_c, feat, perm, xyz_s,
                                                            feat_s, xy_g, feat_g, N);

  // visit emission: one resolution (or pair,res) per blockIdx.y
  visit3_all<0><<<dim3(pb, 3), 256, 0, stream>>>(xyz_s, cnt_v, cur_v, visits, N);
  visit2_all<0><<<dim3(pb, 9), 256, 0, stream>>>(xy_g, cnt_v, cur_v, visits, N);
  scan_blocksum<<<nbv, 256, 0, stream>>>(cnt_v, bsum, KVIS);
  scan_write<<<nbv, 256, 0, stream>>>(cnt_v, bsum, cur_v, KVIS);
  visit3_all<1><<<dim3(pb, 3), 256, 0, stream>>>(xyz_s, cnt_v, cur_v, visits, N);
  visit2_all<1><<<dim3(pb, 9), 256, 0, stream>>>(xy_g, cnt_v, cur_v, visits, N);

  // creates: one dispatch per homogeneous segment (balanced XCD swizzle)
  create_block<<<4096, 256, 0, stream>>>(feat_s, cnt_v, cur_v, visits, grid, KO16);
  create_block<<<32768, 256, 0, stream>>>(feat_s, cnt_v, cur_v, visits, grid, KO32);
  create_wave4<<<262144 / 4, 256, 0, stream>>>(feat_s, cnt_v, cur_v, visits, grid, KO64,
                                               262144);
  create_block<<<12288, 256, 0, stream>>>(feat_g, cnt_v, cur_v, visits, grid, KO64Q);
  create_block<<<49152, 256, 0, stream>>>(feat_g, cnt_v, cur_v, visits, grid, KO128Q);
  create_wave4<<<196608 / 4, 256, 0, stream>>>(feat_g, cnt_v, cur_v, visits, grid,
                                               KO256Q, 196608);

  // fused encode: all 12 slots in one dispatch
  encode_all<<<(M * 32 + 255) / 256, 256, 0, stream>>>(xyz_i, grid, out, M);
}